// Round 1
// baseline (13.228 us; speedup 1.0000x reference)
//
#include <hip/hip_runtime.h>
#include <math.h>

// Analytic simulation:
//  - per-qubit product states tracked as real Bloch vectors (SO(3) rotations),
//  - layer-2 observables O_q = U^dag Z U = n·sigma with n = Rx(-a)Ry(-b) z_hat,
//  - CNOT-ring pullback of each Pauli string via stabilizer (symplectic) update,
//  - expectation of a Pauli string on a product state = product of Bloch components.

__device__ __forceinline__ void brx(float t, float& x, float& y, float& z) {
  float s, c; sincosf(t, &s, &c);
  float y2 = c * y - s * z;
  z = s * y + c * z;
  y = y2;
  (void)x;
}
__device__ __forceinline__ void bry(float t, float& x, float& y, float& z) {
  float s, c; sincosf(t, &s, &c);
  float z2 = c * z - s * x;
  x = s * z + c * x;
  z = z2;
  (void)y;
}
__device__ __forceinline__ void brz(float t, float& x, float& y, float& z) {
  float s, c; sincosf(t, &s, &c);
  float x2 = c * x - s * y;
  y = s * x + c * y;
  x = x2;
  (void)z;
}

__global__ __launch_bounds__(512) void qie_kernel(
    const float* __restrict__ x,     // [8,16,4,3]
    const float* __restrict__ posw,  // [16,2]
    const float* __restrict__ l1w,   // [20,3]
    const float* __restrict__ l2w,   // [16,3]
    const float* __restrict__ hw,    // [512,4]
    const float* __restrict__ hb,    // [512]
    float* __restrict__ out)         // [8,512]
{
  const int img = blockIdx.x;
  const int tid = threadIdx.x;
  const int wid = tid >> 6, lane = tid & 63;

  __shared__ float bl[4][20][3];  // Bloch vectors: [block][qubit][x,y,z]
  __shared__ float nv[16][3];     // observable Bloch vectors
  __shared__ double eg[7];        // group expectations
  __shared__ double qv[4];        // q features
  __shared__ double red[8];       // norm partials
  __shared__ double nrm;

  // ---- Phase A: per-qubit Bloch vectors (threads 0..79) ----
  if (tid < 80) {
    const int b = tid / 20, i = tid % 20;
    const int p = 4 * b + i / 5, j = i % 5;
    float nx = 0.f, ny = 0.f, nz = 1.f;  // |0> = z_hat
    if (j < 4) {
      const float* a = x + ((img * 16 + p) * 4 + j) * 3;
      brx(a[0], nx, ny, nz);
      bry(a[1], nx, ny, nz);
      brz(a[2], nx, ny, nz);
    } else {
      brx(posw[p * 2 + 0], nx, ny, nz);
      bry(posw[p * 2 + 1], nx, ny, nz);
    }
    brx(l1w[i * 3 + 0], nx, ny, nz);
    bry(l1w[i * 3 + 1], nx, ny, nz);
    brz(l1w[i * 3 + 2], nx, ny, nz);
    bl[b][i][0] = nx; bl[b][i][1] = ny; bl[b][i][2] = nz;
  } else if (tid < 96) {
    // ---- Phase B: O_q = n·sigma, n = Rx(-a)Ry(-b) z_hat (Rz drops out) ----
    const int q = tid - 80;
    float sa, ca, sb, cb;
    sincosf(l2w[q * 3 + 0], &sa, &ca);
    sincosf(l2w[q * 3 + 1], &sb, &cb);
    nv[q][0] = -sb;       // X coeff
    nv[q][1] = sa * cb;   // Y coeff
    nv[q][2] = ca * cb;   // Z coeff
  }
  __syncthreads();

  // ---- Phase C: 7 expectation groups, one wave each ----
  // g0..g3: Efull[b] wires {0,1,2,3}; g4: eA wires {1,2,3}; g5: e1 wires {0,1};
  // g6: e2 wires {0,1,2}. Obs index = 4*qb + wire. Wires consecutive from w0.
  double acc = 0.0;
  if (wid < 7) {
    const int g_nw[7] = {4, 4, 4, 4, 3, 2, 3};
    const int g_qb[7] = {0, 1, 2, 3, 0, 0, 0};
    const int g_w0[7] = {0, 0, 0, 0, 1, 0, 0};
    const int nw = g_nw[wid], qb = g_qb[wid], w0 = g_w0[wid];
    int nstr = 1;
    for (int k = 0; k < nw; ++k) nstr *= 3;
    for (int t = lane; t < nstr; t += 64) {
      unsigned xm = 0, zm = 0;
      double coeff = 1.0;
      int tt = t;
      for (int k = 0; k < nw; ++k) {
        const int w = w0 + k;
        const int d = tt % 3;  // 0=X,1=Y,2=Z
        tt /= 3;
        coeff *= (double)nv[4 * qb + w][d];
        if (d != 2) xm |= 1u << w;
        if (d != 0) zm |= 1u << w;
      }
      // Pull back through CNOT ring: psi' = C(19,0)...C(1,2)C(0,1) psi,
      // so conjugate the string by C(19,0) first, ... C(0,1) last.
      unsigned sgn = 0;
      for (int c = 19; c >= 0; --c) {
        const int tq = (c + 1) % 20;
        const unsigned xc = (xm >> c) & 1u, zc = (zm >> c) & 1u;
        const unsigned xt = (xm >> tq) & 1u, zt = (zm >> tq) & 1u;
        sgn ^= xc & zt & (xt ^ zc ^ 1u);
        xm ^= xc << tq;  // x_t ^= x_c
        zm ^= zt << c;   // z_c ^= z_t
      }
      double val = sgn ? -coeff : coeff;
      for (int i = 0; i < 20; ++i) {
        const unsigned xi = (xm >> i) & 1u, zi = (zm >> i) & 1u;
        if (xi | zi) val *= (double)bl[qb][i][xi ? (zi ? 1 : 0) : 2];
      }
      acc += val;
    }
  }
  for (int off = 32; off; off >>= 1) acc += __shfl_xor(acc, off, 64);
  if (wid < 7 && lane == 0) eg[wid] = acc;
  __syncthreads();

  if (tid == 0) {
    qv[0] = eg[4] * eg[1] * eg[2] * eg[3];  // e0
    qv[1] = eg[5];                          // e1
    qv[2] = eg[6];                          // e2
    qv[3] = eg[0];                          // e3 = Efull[0]
  }
  __syncthreads();

  // ---- Phase E: head + L2 normalize (one thread per output) ----
  double y = qv[0] * (double)hw[tid * 4 + 0] + qv[1] * (double)hw[tid * 4 + 1] +
             qv[2] * (double)hw[tid * 4 + 2] + qv[3] * (double)hw[tid * 4 + 3] +
             (double)hb[tid];
  double ss = y * y;
  for (int off = 32; off; off >>= 1) ss += __shfl_xor(ss, off, 64);
  if (lane == 0) red[wid] = ss;
  __syncthreads();
  if (tid == 0) {
    double s = 0.0;
    for (int i = 0; i < 8; ++i) s += red[i];
    nrm = fmax(sqrt(s), 1e-12);
  }
  __syncthreads();
  out[img * 512 + tid] = (float)(y / nrm);
}

extern "C" void kernel_launch(void* const* d_in, const int* in_sizes, int n_in,
                              void* d_out, int out_size, void* d_ws, size_t ws_size,
                              hipStream_t stream) {
  const float* x    = (const float*)d_in[0];  // [8,16,4,3]
  const float* posw = (const float*)d_in[1];  // [16,2]
  const float* l1w  = (const float*)d_in[2];  // [20,3]
  const float* l2w  = (const float*)d_in[3];  // [16,3]
  const float* hw   = (const float*)d_in[4];  // [512,4]
  const float* hb   = (const float*)d_in[5];  // [512]
  float* out = (float*)d_out;                 // [8,512]
  qie_kernel<<<8, 512, 0, stream>>>(x, posw, l1w, l2w, hw, hb, out);
}

// Round 2
// 12.761 us; speedup vs baseline: 1.0366x; 1.0366x over previous
//
#include <hip/hip_runtime.h>
#include <math.h>

// Analytic simulation:
//  - per-qubit product states tracked as real Bloch vectors (SO(3) rotations),
//  - layer-2 observables O_q = U^dag Z U = n·sigma with n = Rx(-a)Ry(-b) z_hat,
//  - CNOT-ring pullback of each Pauli string via stabilizer (symplectic) update,
//  - expectation of a Pauli string on a product state = product of Bloch components.
// All-float version, minimized barrier count (3 syncthreads on critical path).

__device__ __forceinline__ void brx(float t, float& x, float& y, float& z) {
  float s, c; sincosf(t, &s, &c);
  float y2 = c * y - s * z;
  z = s * y + c * z;
  y = y2;
  (void)x;
}
__device__ __forceinline__ void bry(float t, float& x, float& y, float& z) {
  float s, c; sincosf(t, &s, &c);
  float z2 = c * z - s * x;
  x = s * z + c * x;
  z = z2;
  (void)y;
}
__device__ __forceinline__ void brz(float t, float& x, float& y, float& z) {
  float s, c; sincosf(t, &s, &c);
  float x2 = c * x - s * y;
  y = s * x + c * y;
  x = x2;
  (void)z;
}

__global__ __launch_bounds__(512) void qie_kernel(
    const float* __restrict__ x,     // [8,16,4,3]
    const float* __restrict__ posw,  // [16,2]
    const float* __restrict__ l1w,   // [20,3]
    const float* __restrict__ l2w,   // [16,3]
    const float* __restrict__ hw,    // [512,4]
    const float* __restrict__ hb,    // [512]
    float* __restrict__ out)         // [8,512]
{
  const int img = blockIdx.x;
  const int tid = threadIdx.x;
  const int wid = tid >> 6, lane = tid & 63;

  __shared__ float bl[4][20][3];  // Bloch vectors: [block][qubit][x,y,z]
  __shared__ float nv[16][3];     // observable Bloch vectors
  __shared__ float eg[7];         // group expectations
  __shared__ float red[8];        // norm partials

  // ---- Phase A: per-qubit Bloch vectors (threads 0..79) ----
  if (tid < 80) {
    const int b = tid / 20, i = tid % 20;
    const int p = 4 * b + i / 5, j = i % 5;
    float nx = 0.f, ny = 0.f, nz = 1.f;  // |0> = z_hat
    if (j < 4) {
      const float* a = x + ((img * 16 + p) * 4 + j) * 3;
      brx(a[0], nx, ny, nz);
      bry(a[1], nx, ny, nz);
      brz(a[2], nx, ny, nz);
    } else {
      brx(posw[p * 2 + 0], nx, ny, nz);
      bry(posw[p * 2 + 1], nx, ny, nz);
    }
    brx(l1w[i * 3 + 0], nx, ny, nz);
    bry(l1w[i * 3 + 1], nx, ny, nz);
    brz(l1w[i * 3 + 2], nx, ny, nz);
    bl[b][i][0] = nx; bl[b][i][1] = ny; bl[b][i][2] = nz;
  } else if (tid < 96) {
    // ---- Phase B: O_q = n·sigma, n = Rx(-a)Ry(-b) z_hat (Rz drops out) ----
    const int q = tid - 80;
    float sa, ca, sb, cb;
    sincosf(l2w[q * 3 + 0], &sa, &ca);
    sincosf(l2w[q * 3 + 1], &sb, &cb);
    nv[q][0] = -sb;       // X coeff
    nv[q][1] = sa * cb;   // Y coeff
    nv[q][2] = ca * cb;   // Z coeff
  }
  __syncthreads();

  // ---- Phase C: 7 expectation groups, one wave each ----
  // g0..g3: Efull[b] wires {0,1,2,3}; g4: eA wires {1,2,3}; g5: e1 wires {0,1};
  // g6: e2 wires {0,1,2}. Obs index = 4*qb + wire. Wires consecutive from w0.
  float acc = 0.0f;
  if (wid < 7) {
    const int g_nw[7] = {4, 4, 4, 4, 3, 2, 3};
    const int g_qb[7] = {0, 1, 2, 3, 0, 0, 0};
    const int g_w0[7] = {0, 0, 0, 0, 1, 0, 0};
    const int nw = g_nw[wid], qb = g_qb[wid], w0 = g_w0[wid];
    int nstr = 1;
    for (int k = 0; k < nw; ++k) nstr *= 3;
    for (int t = lane; t < nstr; t += 64) {
      unsigned xm = 0, zm = 0;
      float coeff = 1.0f;
      int tt = t;
      for (int k = 0; k < nw; ++k) {
        const int w = w0 + k;
        const int d = tt % 3;  // 0=X,1=Y,2=Z
        tt /= 3;
        coeff *= nv[4 * qb + w][d];
        if (d != 2) xm |= 1u << w;
        if (d != 0) zm |= 1u << w;
      }
      // Pull back through CNOT ring: psi' = C(19,0)...C(1,2)C(0,1) psi,
      // so conjugate the string by C(19,0) first, ... C(0,1) last.
      unsigned sgn = 0;
      for (int c = 19; c >= 0; --c) {
        const int tq = (c + 1) % 20;
        const unsigned xc = (xm >> c) & 1u, zc = (zm >> c) & 1u;
        const unsigned xt = (xm >> tq) & 1u, zt = (zm >> tq) & 1u;
        sgn ^= xc & zt & (xt ^ zc ^ 1u);
        xm ^= xc << tq;  // x_t ^= x_c
        zm ^= zt << c;   // z_c ^= z_t
      }
      float val = sgn ? -coeff : coeff;
      for (int i = 0; i < 20; ++i) {
        const unsigned xi = (xm >> i) & 1u, zi = (zm >> i) & 1u;
        if (xi | zi) val *= bl[qb][i][xi ? (zi ? 1 : 0) : 2];
      }
      acc += val;
    }
  }
  for (int off = 32; off; off >>= 1) acc += __shfl_xor(acc, off, 64);
  if (wid < 7 && lane == 0) eg[wid] = acc;
  __syncthreads();

  // ---- Phase D+E fused: every thread computes qv from eg, then head ----
  const float q0 = eg[4] * eg[1] * eg[2] * eg[3];  // e0
  const float q1 = eg[5];                          // e1
  const float q2 = eg[6];                          // e2
  const float q3 = eg[0];                          // e3 = Efull[0]

  float y = q0 * hw[tid * 4 + 0] + q1 * hw[tid * 4 + 1] +
            q2 * hw[tid * 4 + 2] + q3 * hw[tid * 4 + 3] + hb[tid];
  float ss = y * y;
  for (int off = 32; off; off >>= 1) ss += __shfl_xor(ss, off, 64);
  if (lane == 0) red[wid] = ss;
  __syncthreads();
  float s = red[0] + red[1] + red[2] + red[3] + red[4] + red[5] + red[6] + red[7];
  const float rn = 1.0f / fmaxf(sqrtf(s), 1e-12f);
  out[img * 512 + tid] = y * rn;
}

extern "C" void kernel_launch(void* const* d_in, const int* in_sizes, int n_in,
                              void* d_out, int out_size, void* d_ws, size_t ws_size,
                              hipStream_t stream) {
  const float* x    = (const float*)d_in[0];  // [8,16,4,3]
  const float* posw = (const float*)d_in[1];  // [16,2]
  const float* l1w  = (const float*)d_in[2];  // [20,3]
  const float* l2w  = (const float*)d_in[3];  // [16,3]
  const float* hw   = (const float*)d_in[4];  // [512,4]
  const float* hb   = (const float*)d_in[5];  // [512]
  float* out = (float*)d_out;                 // [8,512]
  qie_kernel<<<8, 512, 0, stream>>>(x, posw, l1w, l2w, hw, hb, out);
}